// Round 6
// baseline (171.840 us; speedup 1.0000x reference)
//
#include <hip/hip_runtime.h>

#define B_ 8
#define C_ 128
#define W_ 4096
#define D_ 16
// D^-0.5 * log2(e): folded into Wq/bq; exp2 domain (v_exp_f32)
#define SCALE2 0.3606737602222409f

typedef short bf16x8 __attribute__((ext_vector_type(8)));
typedef float f32x4 __attribute__((ext_vector_type(4)));

__device__ __forceinline__ unsigned short f2bf(float f) {
    unsigned int u = __float_as_uint(f);
    u += 0x7fffu + ((u >> 16) & 1u);
    return (unsigned short)(u >> 16);
}
// pack two f32 -> u32 of 2 bf16 (TRUNCATED) in ONE v_perm_b32
__device__ __forceinline__ unsigned int pk2bf(float lo, float hi) {
    return __builtin_amdgcn_perm(__float_as_uint(hi), __float_as_uint(lo), 0x07060302u);
}
__device__ __forceinline__ bf16x8 u4_to_bf8(unsigned int a, unsigned int b,
                                            unsigned int c, unsigned int d) {
    union { uint4 u; bf16x8 v; } t;
    t.u = make_uint4(a, b, c, d);
    return t.v;
}
// exp2 all 8 score values of an (A,B) j-tile pair and pack to a K=32 B-fragment
__device__ __forceinline__ bf16x8 exp2pack(f32x4 a, f32x4 b) {
    return u4_to_bf8(
        pk2bf(__builtin_amdgcn_exp2f(a[0]), __builtin_amdgcn_exp2f(a[1])),
        pk2bf(__builtin_amdgcn_exp2f(a[2]), __builtin_amdgcn_exp2f(a[3])),
        pk2bf(__builtin_amdgcn_exp2f(b[0]), __builtin_amdgcn_exp2f(b[1])),
        pk2bf(__builtin_amdgcn_exp2f(b[2]), __builtin_amdgcn_exp2f(b[3])));
}
// LDS chunk swizzle for proj staging: <=2-way banks both directions
__device__ __forceinline__ int xswz(int j, int c8) {
    return c8 ^ (j & 7) ^ ((j >> 3) & 7);
}

// ---------------- prep: Wv -> bf16; [Wq*SCALE2 ; Wk] -> bf16 ----------------
__global__ __launch_bounds__(256) void prep(
    const float* __restrict__ Wq, const float* __restrict__ Wk, const float* __restrict__ Wv,
    unsigned short* __restrict__ Wvbf, unsigned short* __restrict__ Wqkbf)
{
    int g = blockIdx.x * 256 + threadIdx.x;
    const float* src; unsigned short* dst; float sc = 1.0f;
    if (g < 4096)      { src = Wv + g * 4;            dst = Wvbf + g * 4; }
    else if (g < 4608) { int t = g - 4096; src = Wq + t * 4; dst = Wqkbf + t * 4; sc = SCALE2; }
    else               { int t = g - 4608; src = Wk + t * 4; dst = Wqkbf + 2048 + t * 4; }
    float4 v = *(const float4*)src;
    unsigned short h[4] = {f2bf(v.x * sc), f2bf(v.y * sc), f2bf(v.z * sc), f2bf(v.w * sc)};
    *(ushort4*)dst = *(ushort4*)h;
}

// ---------------- proj: q,k,v in one pass (MFMA), j-strip 32, grid 1024 ----------------
// qws/kws: [b][plane 0..3][pos][8] bf16. plane2 of k = {1.0,0...}; plane2 of q
// zeroed here, slot0 later filled with -log2(l) by finl. plane3 = 0.
// vws: j-tiled [b][j/16][c][j%16] bf16
__global__ __launch_bounds__(256) void proj(
    const float* __restrict__ x, const unsigned short* __restrict__ Wvbf,
    const unsigned short* __restrict__ Wqkbf,
    const float* __restrict__ bqp, const float* __restrict__ bkp, const float* __restrict__ bvp,
    unsigned short* __restrict__ qws, unsigned short* __restrict__ kws,
    unsigned short* __restrict__ vws)
{
    __shared__ unsigned short xbf[32 * 128];    // [j][c] swizzled chunks, 8KB
    __shared__ unsigned short outs[128 * 40];   // v-store bounce, 10.2KB

    int b  = blockIdx.x & 7;
    int j0 = (blockIdx.x >> 3) * 32;
    int tid = threadIdx.x;
    int wid = tid >> 6, lane = tid & 63, n = lane & 15, q4 = lane >> 4;

    // stage x tile [128c][32j] -> bf16 LDS [j][c] swizzled
#pragma unroll
    for (int i = 0; i < 4; i++) {
        int idx = tid + 256 * i;                // 1024 float4 slots
        int c = idx >> 3, jc = (idx & 7) * 4;
        float4 t = *(const float4*)(x + (size_t)(b * C_ + c) * W_ + j0 + jc);
        float tv[4] = {t.x, t.y, t.z, t.w};
#pragma unroll
        for (int cc = 0; cc < 4; cc++) {
            int j = jc + cc;
            xbf[j * 128 + xswz(j, c >> 3) * 8 + (c & 7)] = f2bf(tv[cc]);
        }
    }
    __syncthreads();

    const f32x4 zero = {0.f, 0.f, 0.f, 0.f};
    f32x4 accv[2][2]; f32x4 accqk = zero;
#pragma unroll
    for (int os = 0; os < 2; os++)
#pragma unroll
        for (int js = 0; js < 2; js++) accv[os][js] = zero;

    int isK = wid >> 1;          // waves 0,1: q; waves 2,3: k
    int jsm = wid & 1;           // which j-tile this wave's q/k MFMA covers

#pragma unroll
    for (int kk = 0; kk < 128; kk += 32) {
        bf16x8 av[2], aqkf, bx[2];
#pragma unroll
        for (int os = 0; os < 2; os++)
            av[os] = *(const bf16x8*)(Wvbf + (wid * 32 + os * 16 + n) * 128 + kk + q4 * 8);
        aqkf = *(const bf16x8*)(Wqkbf + (isK * 16 + n) * 128 + kk + q4 * 8);
#pragma unroll
        for (int js = 0; js < 2; js++) {
            int j = js * 16 + n;
            bx[js] = *(const bf16x8*)&xbf[j * 128 + xswz(j, (kk >> 3) + q4) * 8];
        }
#pragma unroll
        for (int os = 0; os < 2; os++)
#pragma unroll
            for (int js = 0; js < 2; js++)
                accv[os][js] = __builtin_amdgcn_mfma_f32_16x16x32_bf16(av[os], bx[js], accv[os][js], 0, 0, 0);
        accqk = __builtin_amdgcn_mfma_f32_16x16x32_bf16(aqkf, bx[jsm], accqk, 0, 0, 0);
    }

    // q/k epilogue: wave (isK,jsm) writes 16 positions
    {
        int pos = j0 + jsm * 16 + n;
        const float* bias = isK ? bkp : bqp;
        float bsc = isK ? 1.0f : SCALE2;
        float v0 = accqk[0] + bias[q4 * 4 + 0] * bsc;
        float v1 = accqk[1] + bias[q4 * 4 + 1] * bsc;
        float v2 = accqk[2] + bias[q4 * 4 + 2] * bsc;
        float v3 = accqk[3] + bias[q4 * 4 + 3] * bsc;
        unsigned short* basep = isK ? kws : qws;
        size_t base = ((size_t)(b * 4 + (q4 >> 1)) * W_ + pos) * 8 + (q4 & 1) * 4;
        *(uint2*)(basep + base) = make_uint2((unsigned)f2bf(v0) | ((unsigned)f2bf(v1) << 16),
                                             (unsigned)f2bf(v2) | ((unsigned)f2bf(v3) << 16));
    }
    // planes 2,3: zero, except k plane2 dim16 = 1.0 (bf16 0x3f80)
    if (tid < 128) {
        int which = tid >> 6;                  // 0: q, 1: k
        int plane = 2 + ((tid >> 5) & 1);
        int pos = j0 + (tid & 31);
        unsigned short* basep = which ? kws : qws;
        uint4 z = make_uint4(0, 0, 0, 0);
        if (which == 1 && plane == 2) z.x = 0x3f80u;
        *(uint4*)(basep + ((size_t)(b * 4 + plane) * W_ + pos) * 8) = z;
    }

    // v epilogue -> LDS bounce -> j-tiled layout
    float bvv[2][4];
#pragma unroll
    for (int os = 0; os < 2; os++)
#pragma unroll
        for (int r = 0; r < 4; r++) bvv[os][r] = bvp[wid * 32 + os * 16 + q4 * 4 + r];
#pragma unroll
    for (int os = 0; os < 2; os++)
#pragma unroll
        for (int js = 0; js < 2; js++)
#pragma unroll
            for (int r = 0; r < 4; r++) {
                int c = wid * 32 + os * 16 + q4 * 4 + r;
                int j = js * 16 + n;
                outs[c * 40 + j] = f2bf(accv[os][js][r] + bvv[os][r]);
            }
    __syncthreads();
    {
        int jt_l = tid >> 7;          // 0..1
        int c    = tid & 127;
        const uint4* src = (const uint4*)&outs[c * 40 + jt_l * 16];
        unsigned short* dst = vws + ((size_t)((b * 256 + (j0 >> 4) + jt_l) * 128 + c)) * 16;
        *(uint4*)(dst + 0) = src[0];
        *(uint4*)(dst + 8) = src[1];
    }
}

// ---------------- row_stats: partial l-sums, w split 4 ways, pipelined ----------------
__global__ __launch_bounds__(256) void row_stats(
    const unsigned short* __restrict__ qws, const unsigned short* __restrict__ kws,
    float* __restrict__ rlp)
{
    int blk = blockIdx.x;
    int b = blk & 7;
    int j0 = ((blk >> 3) & 63) * 64;
    int wsp = blk >> 9;                 // 0..3
    int t0 = wsp * 16;                  // 16 key tiles of 64
    int tid = threadIdx.x;
    int wid = tid >> 6, lane = tid & 63, n = lane & 15, q4 = lane >> 4;

    const bf16x8* qbase = (const bf16x8*)qws + (size_t)(b * 4 + q4) * W_;
    const bf16x8* kbase = (const bf16x8*)kws + (size_t)(b * 4 + q4) * W_;
    bf16x8 aq = qbase[j0 + wid * 16 + n];
    const f32x4 zero = {0.f, 0.f, 0.f, 0.f};

    float lt[4] = {0.f, 0.f, 0.f, 0.f};
    bf16x8 k0[4], k1[4];
#pragma unroll
    for (int ws = 0; ws < 4; ws++) {
        k0[ws] = kbase[(t0 + 0) * 64 + ws * 16 + n];
        k1[ws] = kbase[(t0 + 1) * 64 + ws * 16 + n];
    }

#pragma unroll 2
    for (int t = 0; t < 8; t++) {
        f32x4 sa[4], sb[4];
#pragma unroll
        for (int ws = 0; ws < 4; ws++)
            sa[ws] = __builtin_amdgcn_mfma_f32_16x16x32_bf16(aq, k0[ws], zero, 0, 0, 0);
#pragma unroll
        for (int ws = 0; ws < 4; ws++)
            sb[ws] = __builtin_amdgcn_mfma_f32_16x16x32_bf16(aq, k1[ws], zero, 0, 0, 0);
        int ta = t0 + ((2 * t + 2) & 15), tb = t0 + ((2 * t + 3) & 15);
#pragma unroll
        for (int ws = 0; ws < 4; ws++) {
            k0[ws] = kbase[ta * 64 + ws * 16 + n];
            k1[ws] = kbase[tb * 64 + ws * 16 + n];
        }
#pragma unroll
        for (int ws = 0; ws < 4; ws++)
#pragma unroll
            for (int r = 0; r < 4; r++) {
                lt[r] += __builtin_amdgcn_exp2f(sa[ws][r]);
                lt[r] += __builtin_amdgcn_exp2f(sb[ws][r]);
            }
    }
#pragma unroll
    for (int mask = 1; mask < 16; mask <<= 1)
#pragma unroll
        for (int r = 0; r < 4; r++) lt[r] += __shfl_xor(lt[r], mask, 64);
    if (n == 0) {
        f32x4 l4 = {lt[0], lt[1], lt[2], lt[3]};
        *(f32x4*)(rlp + (size_t)wsp * 32768 + (size_t)b * W_ + j0 + wid * 16 + q4 * 4) = l4;
    }
}

// ---------------- finl: l = sum of 4 partials; q plane2 slot0 <- -log2(l) ----------------
__global__ __launch_bounds__(256) void finl(const float* __restrict__ rlp,
                                            unsigned short* __restrict__ qws)
{
    int g = blockIdx.x * 256 + threadIdx.x;   // 32768 = B*W
    int b = g >> 12, j = g & (W_ - 1);
    float l = rlp[g] + rlp[32768 + g] + rlp[65536 + g] + rlp[98304 + g];
    qws[((size_t)(b * 4 + 2) * W_ + j) * 8] = f2bf(-__builtin_amdgcn_logf(l));
}

// ---------------- attn_out: 8 waves, barrier-free K-loop, tree reduction ----------------
__global__ __launch_bounds__(512, 1) void attn_out(
    const float* __restrict__ x, const unsigned short* __restrict__ qws,
    const unsigned short* __restrict__ kws, const unsigned short* __restrict__ vws,
    float* __restrict__ out)
{
    __shared__ float bufA[128 * 68];   // 34.8KB
    __shared__ float bufB[128 * 68];   // 34.8KB

    int b  = blockIdx.x & 7;
    int w0 = (blockIdx.x >> 3) * 64;
    int tid = threadIdx.x;
    int wid = tid >> 6, lane = tid & 63, n = lane & 15, q4 = lane >> 4;

    const bf16x8* qbase = (const bf16x8*)qws + (size_t)(b * 4 + q4) * W_;
    const bf16x8* kbase = (const bf16x8*)kws + (size_t)(b * 4 + q4) * W_;
    const unsigned short* vtb = vws + (size_t)b * 256 * 128 * 16;

    bf16x8 bk[4];
#pragma unroll
    for (int ws = 0; ws < 4; ws++) bk[ws] = kbase[w0 + ws * 16 + n];

    const f32x4 zero = {0.f, 0.f, 0.f, 0.f};
    f32x4 acc[8][4];   // [mt(c)][nt(w)]
#pragma unroll
    for (int mt = 0; mt < 8; mt++)
#pragma unroll
        for (int nt = 0; nt < 4; nt++) acc[mt][nt] = zero;

    // ---- pipeline prologue (it = 0): wave owns j-tiles {it*16+wid*2, +1} ----
    bf16x8 aqA = qbase[wid * 32 + n];
    bf16x8 aqB = qbase[wid * 32 + 16 + n];
    uint2 vfA[8], vfB[8];
#pragma unroll
    for (int mt = 0; mt < 8; mt++) {
        int c = mt * 16 + n;
        vfA[mt] = *(const uint2*)(vtb + (size_t)((wid * 2 + 0) * 128 + c) * 16 + q4 * 4);
        vfB[mt] = *(const uint2*)(vtb + (size_t)((wid * 2 + 1) * 128 + c) * 16 + q4 * 4);
    }
    f32x4 sA[4], sB[4];
#pragma unroll
    for (int ws = 0; ws < 4; ws++) {
        sA[ws] = __builtin_amdgcn_mfma_f32_16x16x32_bf16(aqA, bk[ws], zero, 0, 0, 0);
        sB[ws] = __builtin_amdgcn_mfma_f32_16x16x32_bf16(aqB, bk[ws], zero, 0, 0, 0);
    }
    aqA = qbase[256 + wid * 32 + n];          // q frags for it=1
    aqB = qbase[256 + wid * 32 + 16 + n];
    bf16x8 bfrag[4];
#pragma unroll
    for (int ws = 0; ws < 4; ws++) bfrag[ws] = exp2pack(sA[ws], sB[ws]);

    for (int it = 0; it < 16; it++) {
        int itn = (it + 1) & 15;
        // (a) v-fragment prefetch for it+1
        uint2 vfA_n[8], vfB_n[8];
        int jtA_n = itn * 16 + wid * 2, jtB_n = jtA_n + 1;
#pragma unroll
        for (int mt = 0; mt < 8; mt++) {
            int c = mt * 16 + n;
            vfA_n[mt] = *(const uint2*)(vtb + (size_t)(jtA_n * 128 + c) * 16 + q4 * 4);
            vfB_n[mt] = *(const uint2*)(vtb + (size_t)(jtB_n * 128 + c) * 16 + q4 * 4);
        }
        // (b) S-MFMAs for it+1 (aq regs hold it+1 frags)
#pragma unroll
        for (int ws = 0; ws < 4; ws++) {
            sA[ws] = __builtin_amdgcn_mfma_f32_16x16x32_bf16(aqA, bk[ws], zero, 0, 0, 0);
            sB[ws] = __builtin_amdgcn_mfma_f32_16x16x32_bf16(aqB, bk[ws], zero, 0, 0, 0);
        }
        // (c) q loads for it+2
        int itn2 = (it + 2) & 15;
        aqA = qbase[itn2 * 256 + wid * 32 + n];
        aqB = qbase[itn2 * 256 + wid * 32 + 16 + n];
        // (d) PV for it (consumes bfrag + vf regs)
#pragma unroll
        for (int mt = 0; mt < 8; mt++) {
            bf16x8 af = u4_to_bf8(vfA[mt].x, vfA[mt].y, vfB[mt].x, vfB[mt].y);
#pragma unroll
            for (int nt = 0; nt < 4; nt++)
                acc[mt][nt] = __builtin_amdgcn_mfma_f32_16x16x32_bf16(af, bfrag[nt], acc[mt][nt], 0, 0, 0);
        }
        // (e) exp2/pack for it+1 -> next bfrag
#pragma unroll
        for (int ws = 0; ws < 4; ws++) bfrag[ws] = exp2pack(sA[ws], sB[ws]);
        // rotate v-frag registers
#pragma unroll
        for (int mt = 0; mt < 8; mt++) { vfA[mt] = vfA_n[mt]; vfB[mt] = vfB_n[mt]; }
    }

    // ---- tree reduction over 8 wave-tiles via 2 buffers ----
#define WRITE_TILE(BUF)                                                          \
    {                                                                            \
        float* _b = (BUF);                                                       \
        _Pragma("unroll") for (int mt = 0; mt < 8; mt++)                         \
        _Pragma("unroll") for (int nt = 0; nt < 4; nt++)                         \
        _Pragma("unroll") for (int r = 0; r < 4; r++)                            \
            _b[(mt * 16 + q4 * 4 + r) * 68 + nt * 16 + n] = acc[mt][nt][r];      \
    }
#define ADD_TILE(BUF)                                                            \
    {                                                                            \
        const float* _b = (BUF);                                                 \
        _Pragma("unroll") for (int mt = 0; mt < 8; mt++)                         \
        _Pragma("unroll") for (int nt = 0; nt < 4; nt++)                         \
        _Pragma("unroll") for (int r = 0; r < 4; r++)                            \
            acc[mt][nt][r] += _b[(mt * 16 + q4 * 4 + r) * 68 + nt * 16 + n];     \
    }
    if (wid == 1) WRITE_TILE(bufA);
    if (wid == 3) WRITE_TILE(bufB);
    __syncthreads();
    if (wid == 0) ADD_TILE(bufA);
    if (wid == 2) ADD_TILE(bufB);
    __syncthreads();
    if (wid == 5) WRITE_TILE(bufA);
    if (wid == 7) WRITE_TILE(bufB);
    __syncthreads();
    if (wid == 4) ADD_TILE(bufA);
    if (wid == 6) ADD_TILE(bufB);
    __syncthreads();
    if (wid == 2) WRITE_TILE(bufA);
    if (wid == 6) WRITE_TILE(bufB);
    __syncthreads();
    if (wid == 0) ADD_TILE(bufA);
    if (wid == 4) ADD_TILE(bufB);
    __syncthreads();
    if (wid == 4) WRITE_TILE(bufA);
    __syncthreads();
    if (wid == 0) { ADD_TILE(bufA); WRITE_TILE(bufA); }
    __syncthreads();
#undef WRITE_TILE
#undef ADD_TILE

    // coalesced store: out = bufA + x (512 threads x 4 float4)
#pragma unroll
    for (int u = 0; u < 4; u++) {
        int k = tid + 512 * u;          // 2048 float4 slots
        int c = k >> 4, wseg = (k & 15) * 4;
        size_t gidx = (size_t)(b * C_ + c) * W_ + w0 + wseg;
        float4 xv = *(const float4*)(x + gidx);
        const float* s = &bufA[c * 68 + wseg];
        float4 o = make_float4(s[0] + xv.x, s[1] + xv.y, s[2] + xv.z, s[3] + xv.w);
        *(float4*)(out + gidx) = o;
    }
}

extern "C" void kernel_launch(void* const* d_in, const int* in_sizes, int n_in,
                              void* d_out, int out_size, void* d_ws, size_t ws_size,
                              hipStream_t stream)
{
    const float* x  = (const float*)d_in[0];
    const float* Wq = (const float*)d_in[1];
    const float* bq = (const float*)d_in[2];
    const float* Wk = (const float*)d_in[3];
    const float* bk = (const float*)d_in[4];
    const float* Wv = (const float*)d_in[5];
    const float* bv = (const float*)d_in[6];
    float* out = (float*)d_out;

    unsigned short* qws  = (unsigned short*)d_ws;        // [B][4][W][8] bf16 = 2MB
    unsigned short* kws  = qws + (size_t)1048576;        // [B][4][W][8] bf16 = 2MB
    unsigned short* vws  = kws + (size_t)1048576;        // [B][W/16][C][16] bf16 = 8MB
    unsigned short* Wvbf = vws + (size_t)4194304;        // [128][128]
    unsigned short* Wqkbf = Wvbf + 16384;                // [32][128] (q rows pre-scaled)
    float* rlp = (float*)(Wqkbf + 4096);                 // [4][B][W] partial l-sums

    prep<<<20, 256, 0, stream>>>(Wq, Wk, Wv, Wvbf, Wqkbf);
    proj<<<1024, 256, 0, stream>>>(x, Wvbf, Wqkbf, bq, bk, bv, qws, kws, vws);
    row_stats<<<2048, 256, 0, stream>>>(qws, kws, rlp);
    finl<<<128, 256, 0, stream>>>(rlp, qws);
    attn_out<<<512, 512, 0, stream>>>(x, qws, kws, vws, out);
}